// Round 1
// baseline (1866.208 us; speedup 1.0000x reference)
//
#include <hip/hip_runtime.h>

#define NTOK 577
#define BATCH 4
#define HEADS 12
#define LAYERS 12
#define CDIM 768
#define SSEL 57
#define KEEP 58
#define MROWS (BATCH * NTOK)  // 2308
#define NR 10                 // ceil(577/64) register slots per lane
#define IC 16                 // i-chunks for vmul partials

// mega-kernel block partition: [init | KV-gemm | fuse]
#define NINIT 10
#define NKVT ((MROWS + 63) / 64)      // 37 M-tiles
#define NKV (2 * NKVT * (CDIM / 64))  // 888 blocks (K and V)
#define NFUSE (LAYERS * MROWS / 4)    // 6924 blocks
#define NB_CHAIN (BATCH * 3 * IC)     // 192 persistent blocks

// ---------------------------------------------------------------------------
// gemm tile body: C[m,n] = sum_c A[m,c]*W[n,c] + bias[n]; K = CDIM = 768.
// 64x64 tile, BK=16, 256 threads, 4x4 microtile. Optional row gather.
// (identical numerics to the verified gemm_nt)
// ---------------------------------------------------------------------------
__device__ __forceinline__ void gemm_tile(int bx, int by,
                                          const float* __restrict__ A,
                                          const float* __restrict__ W,
                                          const float* __restrict__ bias,
                                          float* __restrict__ C, int M,
                                          const int* __restrict__ rowidx,
                                          float (*As)[68], float (*Bs)[68]) {
  const int tid = threadIdx.x;
  const int lm = tid >> 2;
  const int lk = (tid & 3) << 2;
  const int mrow = bx * 64 + lm;
  const bool mv = (mrow < M);
  const float* Abase = A;
  if (mv) {
    int ridx = rowidx ? rowidx[mrow] : mrow;
    Abase = A + (size_t)ridx * CDIM;
  }
  const int nrow = by * 64 + lm;
  const float* Wbase = W + (size_t)nrow * CDIM;

  const int m0 = (tid & 15) << 2;
  const int n0 = (tid >> 4) << 2;
  float acc[4][4] = {{0.f}};

  for (int k0 = 0; k0 < CDIM; k0 += 16) {
    float4 av = mv ? *(const float4*)(Abase + k0 + lk) : make_float4(0.f, 0.f, 0.f, 0.f);
    float4 bv = *(const float4*)(Wbase + k0 + lk);
    __syncthreads();
    As[lk + 0][lm] = av.x; As[lk + 1][lm] = av.y;
    As[lk + 2][lm] = av.z; As[lk + 3][lm] = av.w;
    Bs[lk + 0][lm] = bv.x; Bs[lk + 1][lm] = bv.y;
    Bs[lk + 2][lm] = bv.z; Bs[lk + 3][lm] = bv.w;
    __syncthreads();
#pragma unroll
    for (int k = 0; k < 16; ++k) {
      float a0 = As[k][m0 + 0], a1 = As[k][m0 + 1], a2 = As[k][m0 + 2], a3 = As[k][m0 + 3];
      float b0 = Bs[k][n0 + 0], b1 = Bs[k][n0 + 1], b2 = Bs[k][n0 + 2], b3 = Bs[k][n0 + 3];
      acc[0][0] += a0 * b0; acc[0][1] += a0 * b1; acc[0][2] += a0 * b2; acc[0][3] += a0 * b3;
      acc[1][0] += a1 * b0; acc[1][1] += a1 * b1; acc[1][2] += a1 * b2; acc[1][3] += a1 * b3;
      acc[2][0] += a2 * b0; acc[2][1] += a2 * b1; acc[2][2] += a2 * b2; acc[2][3] += a2 * b3;
      acc[3][0] += a3 * b0; acc[3][1] += a3 * b1; acc[3][2] += a3 * b2; acc[3][3] += a3 * b3;
    }
  }
  const int cmBase = bx * 64 + m0;
  const int cnBase = by * 64 + n0;
#pragma unroll
  for (int ii = 0; ii < 4; ++ii) {
    int cm = cmBase + ii;
    if (cm < M) {
      float* crow = C + (size_t)cm * CDIM + cnBase;
#pragma unroll
      for (int jj = 0; jj < 4; ++jj) crow[jj] = acc[ii][jj] + bias[cnBase + jj];
    }
  }
}

// ---------------------------------------------------------------------------
// mega1: ONE launch = init zeroing + K-gemm + V-gemm + fuse_all.
// GEMM blocks are placed FIRST so the compute-bound GEMM overlaps the
// BW-bound fuse_all instead of serializing after it.
// ---------------------------------------------------------------------------
__global__ __launch_bounds__(256) void mega1(
    const float* __restrict__ ah, float* __restrict__ Abuf,
    const float* __restrict__ x, const float* __restrict__ Wk,
    const float* __restrict__ bk, float* __restrict__ kbuf,
    const float* __restrict__ Wv, const float* __restrict__ bv,
    float* __restrict__ vbuf, int* __restrict__ selpos,
    int* __restrict__ unionm, int* __restrict__ barcnt) {
  __shared__ float As[16][68];
  __shared__ float Bs[16][68];
  const int bx = blockIdx.x;
  const int tid = threadIdx.x;

  if (bx < NINIT) {  // --- init: zero masks + chain barrier counters ---
    int i = bx * 256 + tid;
    if (i < MROWS) selpos[i] = 0;
    if (i < NTOK) unionm[i] = 0;
    if (i < 16) barcnt[i] = 0;
    return;
  }

  if (bx < NINIT + NKV) {  // --- K and V gemms (independent of fuse) ---
    const int idx = bx - NINIT;
    const int which = idx / (NKV / 2);
    const int r = idx % (NKV / 2);
    const int gx = r % NKVT;
    const int gy = r / NKVT;
    if (which == 0)
      gemm_tile(gx, gy, x, Wk, bk, kbuf, MROWS, nullptr, As, Bs);
    else
      gemm_tile(gx, gy, x, Wv, bv, vbuf, MROWS, nullptr, As, Bs);
    return;
  }

  // --- fuse_all: one wave per (layer, b, row i), all 12 layers ---
  const int w = (bx - NINIT - NKV) * 4 + (tid >> 6);  // wave id, < 27696
  const int lane = tid & 63;
  const int l = w / (BATCH * NTOK);
  const int rr = w % (BATCH * NTOK);
  const int b = rr / NTOK;
  const int i = rr % NTOK;
  const float* base =
      ah + ((((size_t)l * BATCH + b) * HEADS) * NTOK + i) * NTOK;

  float val[NR];
  unsigned ub[NR];
#pragma unroll
  for (int r = 0; r < NR; ++r) {
    const int j = lane + 64 * r;
    float s = 0.f;
    if (j < NTOK) {
#pragma unroll
      for (int h = 0; h < HEADS; ++h)
        s += __builtin_nontemporal_load(&base[(size_t)h * NTOK * NTOK + j]);
      s = s / 12.f;  // same op order as the verified version
    }
    val[r] = s;
    ub[r] = (j < NTOK) ? __float_as_uint(s) : 0u;
  }

  // binary search: tau = bit pattern of KEEP-th largest
  unsigned tau = 0u;
  for (int bit = 30; bit >= 0; --bit) {
    const unsigned cand = tau | (1u << bit);
    int c = 0;
#pragma unroll
    for (int r = 0; r < NR; ++r) c += ((ub[r] >> bit) >= (cand >> bit));
#pragma unroll
    for (int off = 1; off < 64; off <<= 1) c += __shfl_xor(c, off, 64);
    if (c >= KEEP) tau = cand;
  }

  int cgt = 0;
#pragma unroll
  for (int r = 0; r < NR; ++r) cgt += (ub[r] > tau);
#pragma unroll
  for (int off = 1; off < 64; off <<= 1) cgt += __shfl_xor(cgt, off, 64);
  const int keq = KEEP - cgt;

  unsigned long long em[NR];
#pragma unroll
  for (int r = 0; r < NR; ++r) em[r] = __ballot(ub[r] == tau);
  const unsigned long long ltm = (1ull << lane) - 1ull;

  bool kp[NR];
  int pre = 0;
  float ksum = 0.f;
#pragma unroll
  for (int r = 0; r < NR; ++r) {
    const int j = lane + 64 * r;
    bool k1 = (ub[r] > tau);
    if (ub[r] == tau) {
      const int rank = pre + __popcll(em[r] & ltm);
      k1 = (rank < keq);
    }
    if (j == 0) k1 = true;  // CLS column always kept
    kp[r] = k1;
    if (k1) ksum += val[r];
    pre += __popcll(em[r]);
  }
#pragma unroll
  for (int off = 1; off < 64; off <<= 1) ksum += __shfl_xor(ksum, off, 64);
  const float inv = 1.f / (ksum + 1.f);

  float* Arow = Abuf + (((size_t)(l * BATCH + b) * NTOK) + i) * NTOK;
#pragma unroll
  for (int r = 0; r < NR; ++r) {
    const int j = lane + 64 * r;
    if (j < NTOK)
      Arow[j] = ((kp[r] ? val[r] : 0.f) + ((j == i) ? 1.f : 0.f)) * inv;
  }
}

// ---------------------------------------------------------------------------
// device-scope grid barrier for the persistent chain kernel.
// 192 blocks <= 256 CUs -> co-residency guaranteed. __syncthreads drains
// vmcnt before the release-add; acquire side invalidates per-CU L1 via
// __threadfence so cross-CU partials are re-fetched from L2.
// ---------------------------------------------------------------------------
__device__ __forceinline__ void grid_barrier(int* cnt, int nb) {
  __syncthreads();
  if (threadIdx.x == 0) {
    __hip_atomic_fetch_add(cnt, 1, __ATOMIC_RELEASE, __HIP_MEMORY_SCOPE_AGENT);
    while (__hip_atomic_load(cnt, __ATOMIC_RELAXED, __HIP_MEMORY_SCOPE_AGENT) < nb)
      __builtin_amdgcn_s_sleep(2);
  }
  __syncthreads();
  __threadfence();
}

// ---------------------------------------------------------------------------
// chain_kernel: persistent 192-block kernel doing ALL 12 vector-matrix steps
// (identical work split and fold order as the 12 vmul_part launches) plus the
// final top-k, replacing 13 serial launches with one.
// ---------------------------------------------------------------------------
__global__ __launch_bounds__(256) void chain_kernel(
    const float* __restrict__ Abuf, float* __restrict__ partA,
    float* __restrict__ partB, int* __restrict__ barcnt,
    int* __restrict__ sel, int* __restrict__ selpos,
    int* __restrict__ unionm, int* __restrict__ rowidx) {
  const int blk = blockIdx.x;
  const int tid = threadIdx.x;
  const int ic = blk / 12;
  const int rem = blk % 12;
  const int b = rem / 3;
  const int jc = rem % 3;
  __shared__ float vsh[NTOK];
  const int j = jc * 256 + tid;
  const int i0 = ic * 36;
  const int i1 = (ic == IC - 1) ? NTOK : (i0 + 36);

  for (int t = 0; t < LAYERS; ++t) {
    const int l = LAYERS - 1 - t;
    const float* pin = (t == 0) ? nullptr : ((t & 1) ? partA : partB);
    float* pout = (t & 1) ? partB : partA;
    for (int tt = tid; tt < NTOK; tt += 256) {
      float s;
      if (pin) {
        s = 0.f;
#pragma unroll
        for (int c = 0; c < IC; ++c) s += pin[c * MROWS + b * NTOK + tt];
      } else {
        s = (tt == 0) ? 1.f : 0.f;
      }
      vsh[tt] = s;
    }
    __syncthreads();
    if (j < NTOK) {
      const float* Ab =
          Abuf + (size_t)l * BATCH * NTOK * NTOK + (size_t)b * NTOK * NTOK + j;
      float acc = 0.f;
      for (int i = i0; i < i1; ++i) acc += vsh[i] * Ab[(size_t)i * NTOK];
      pout[ic * MROWS + b * NTOK + j] = acc;
    }
    grid_barrier(&barcnt[t], NB_CHAIN);
  }

  // ---- top-k: blocks 0..3 (one per batch), wave 0 only ----
  if (blk < BATCH && tid < 64) {
    const int bb = blk;
    const int lane = tid;
    unsigned long long key[NR];
#pragma unroll
    for (int r = 0; r < NR; ++r) {
      const int n = lane + 64 * r;
      unsigned long long k2 = 0ull;
      if (n >= 1 && n < NTOK) {
        float s = 0.f;
#pragma unroll
        for (int c = 0; c < IC; ++c) s += partB[c * MROWS + bb * NTOK + n];
        k2 = (((unsigned long long)__float_as_uint(s)) << 32) |
             (unsigned long long)(0xFFFFFFFFu - (unsigned)n);
      }
      key[r] = k2;
    }
    for (int s = 0; s < SSEL; ++s) {
      unsigned long long mk = 0ull;
#pragma unroll
      for (int r = 0; r < NR; ++r) mk = (key[r] > mk) ? key[r] : mk;
#pragma unroll
      for (int off = 1; off < 64; off <<= 1) {
        unsigned long long o = __shfl_xor(mk, off, 64);
        if (o > mk) mk = o;
      }
      const int n = (int)(0xFFFFFFFFu - (unsigned)(mk & 0xFFFFFFFFull));
#pragma unroll
      for (int r = 0; r < NR; ++r)
        if (key[r] == mk) key[r] = 0ull;
      if (lane == 0) {
        sel[bb * SSEL + s] = n;
        selpos[bb * NTOK + n] = s + 1;
        unionm[n] = 1;
        rowidx[bb * SSEL + s] = bb * NTOK + n;
      }
    }
  }
}

// ---------------------------------------------------------------------------
// standalone gemm for Q (row-gathered) and O projections
// ---------------------------------------------------------------------------
__global__ __launch_bounds__(256) void gemm_nt(const float* __restrict__ A,
                                               const float* __restrict__ W,
                                               const float* __restrict__ bias,
                                               float* __restrict__ C, int M,
                                               const int* __restrict__ rowidx) {
  __shared__ float As[16][68];
  __shared__ float Bs[16][68];
  gemm_tile(blockIdx.x, blockIdx.y, A, W, bias, C, M, rowidx, As, Bs);
}

// ---------------------------------------------------------------------------
// attention: block per (b, h, chunk-of-8-queries). S=QK^T*0.125, row softmax
// (attn_w streamed to d_out), O = P@V into obuf (head-merged layout).
// ---------------------------------------------------------------------------
__global__ __launch_bounds__(256) void attn_kernel(const float* __restrict__ qbuf,
                                                   const float* __restrict__ kbuf,
                                                   const float* __restrict__ vbuf,
                                                   float* __restrict__ attnw,
                                                   float* __restrict__ obuf) {
  const int bx = blockIdx.x;
  const int b = bx / (HEADS * 8);
  const int rem = bx % (HEADS * 8);
  const int h = rem / 8;
  const int ch = rem % 8;
  const int s0 = ch * 8;
  int ns = SSEL - s0;
  if (ns > 8) ns = 8;
  const int tid = threadIdx.x;
  __shared__ float Q[8][64];
  __shared__ float P[8][580];
  __shared__ float sred[4];
  __shared__ float sbc;

  for (int t = tid; t < 512; t += 256) {
    int s = t >> 6, d = t & 63;
    Q[s][d] = (s < ns) ? qbuf[((size_t)(b * SSEL + s0 + s)) * CDIM + h * 64 + d] : 0.f;
  }
  __syncthreads();

  for (int e = tid; e < ns * NTOK; e += 256) {
    int s = e / NTOK, n = e % NTOK;
    const float* kr = kbuf + ((size_t)(b * NTOK + n)) * CDIM + h * 64;
    float acc = 0.f;
#pragma unroll
    for (int d = 0; d < 64; ++d) acc += Q[s][d] * kr[d];
    P[s][n] = acc * 0.125f;
  }
  __syncthreads();

  for (int s = 0; s < ns; ++s) {
    float m = -1e30f;
    for (int n = tid; n < NTOK; n += 256) m = fmaxf(m, P[s][n]);
    for (int off = 32; off; off >>= 1) m = fmaxf(m, __shfl_down(m, off, 64));
    if ((tid & 63) == 0) sred[tid >> 6] = m;
    __syncthreads();
    if (tid == 0) sbc = fmaxf(fmaxf(sred[0], sred[1]), fmaxf(sred[2], sred[3]));
    __syncthreads();
    m = sbc;
    float lsum = 0.f;
    for (int n = tid; n < NTOK; n += 256) {
      float e_ = expf(P[s][n] - m);
      P[s][n] = e_;
      lsum += e_;
    }
    for (int off = 32; off; off >>= 1) lsum += __shfl_down(lsum, off, 64);
    if ((tid & 63) == 0) sred[tid >> 6] = lsum;
    __syncthreads();
    if (tid == 0) sbc = 1.f / (sred[0] + sred[1] + sred[2] + sred[3]);
    __syncthreads();
    float inv = sbc;
    float* aw = attnw + ((size_t)((b * HEADS + h) * SSEL + s0 + s)) * NTOK;
    for (int n = tid; n < NTOK; n += 256) {
      float p = P[s][n] * inv;
      P[s][n] = p;
      aw[n] = p;
    }
    __syncthreads();
  }

  for (int t = tid; t < ns * 64; t += 256) {
    int s = t >> 6, d = t & 63;
    float acc = 0.f;
    for (int n = 0; n < NTOK; ++n)
      acc += P[s][n] * vbuf[((size_t)(b * NTOK + n)) * CDIM + h * 64 + d];
    obuf[((size_t)(b * SSEL + s0 + s)) * CDIM + h * 64 + d] = acc;
  }
}

// ---------------------------------------------------------------------------
// scatter: output[b,0]=x; selected -> o2 row; union-selected-elsewhere -> 0;
// otherwise -> x.
// ---------------------------------------------------------------------------
__global__ void scatter_kernel(const float* __restrict__ x, const float* __restrict__ o2,
                               const int* __restrict__ selpos,
                               const int* __restrict__ unionmask,
                               float* __restrict__ out) {
  int idx = blockIdx.x * 256 + threadIdx.x;
  const int total = BATCH * NTOK * CDIM;
  if (idx >= total) return;
  int b = idx / (NTOK * CDIM);
  int r = idx % (NTOK * CDIM);
  int n = r / CDIM;
  int c = r % CDIM;
  float val;
  if (n == 0) {
    val = x[idx];
  } else {
    int sp = selpos[b * NTOK + n];
    if (sp > 0)
      val = o2[((size_t)(b * SSEL + sp - 1)) * CDIM + c];
    else if (unionmask[n])
      val = 0.f;
    else
      val = x[idx];
  }
  out[idx] = val;
}

// ---------------------------------------------------------------------------
extern "C" void kernel_launch(void* const* d_in, const int* in_sizes, int n_in,
                              void* d_out, int out_size, void* d_ws, size_t ws_size,
                              hipStream_t stream) {
  const float* x = (const float*)d_in[0];
  const float* ah = (const float*)d_in[1];
  const float* Wq = (const float*)d_in[2];
  const float* bq = (const float*)d_in[3];
  const float* Wk = (const float*)d_in[4];
  const float* bk = (const float*)d_in[5];
  const float* Wv = (const float*)d_in[6];
  const float* bv = (const float*)d_in[7];
  const float* Wo = (const float*)d_in[8];
  const float* bo = (const float*)d_in[9];
  float* out = (float*)d_out;
  float* attnw = out + (size_t)BATCH * NTOK * CDIM;

  char* w = (char*)d_ws;
  auto carve = [&](size_t bytes) -> char* {
    char* p = w;
    w += (bytes + 255) & ~(size_t)255;
    return p;
  };
  float* Abuf = (float*)carve((size_t)LAYERS * BATCH * NTOK * NTOK * 4);  // 64 MB
  float* partA = (float*)carve((size_t)IC * MROWS * 4);
  float* partB = (float*)carve((size_t)IC * MROWS * 4);
  float* kbuf = (float*)carve((size_t)MROWS * CDIM * 4);
  float* vbuf = (float*)carve((size_t)MROWS * CDIM * 4);
  float* qbuf = (float*)carve((size_t)BATCH * SSEL * CDIM * 4);
  float* obuf = (float*)carve((size_t)BATCH * SSEL * CDIM * 4);
  float* o2buf = (float*)carve((size_t)BATCH * SSEL * CDIM * 4);
  int* selbuf = (int*)carve((size_t)BATCH * SSEL * 4);
  int* selpos = (int*)carve((size_t)BATCH * NTOK * 4);
  int* unionm = (int*)carve((size_t)NTOK * 4);
  int* rowidx = (int*)carve((size_t)BATCH * SSEL * 4);
  int* barcnt = (int*)carve((size_t)16 * 4);

  // 1) init + K-gemm + V-gemm + all-12-layer fuse in ONE launch
  mega1<<<NINIT + NKV + NFUSE, 256, 0, stream>>>(
      ah, Abuf, x, Wk, bk, kbuf, Wv, bv, vbuf, selpos, unionm, barcnt);

  // 2) entire rollout vector chain + topk in ONE persistent launch
  chain_kernel<<<NB_CHAIN, 256, 0, stream>>>(Abuf, partA, partB, barcnt,
                                             selbuf, selpos, unionm, rowidx);

  // 3) tail: Q-gemm (gathered), attention, O-gemm, scatter
  dim3 gQ((BATCH * SSEL + 63) / 64, CDIM / 64);
  gemm_nt<<<gQ, 256, 0, stream>>>(x, Wq, bq, qbuf, BATCH * SSEL, rowidx);
  attn_kernel<<<BATCH * HEADS * 8, 256, 0, stream>>>(qbuf, kbuf, vbuf, attnw, obuf);
  gemm_nt<<<gQ, 256, 0, stream>>>(obuf, Wo, bo, o2buf, BATCH * SSEL, nullptr);
  scatter_kernel<<<(BATCH * NTOK * CDIM + 255) / 256, 256, 0, stream>>>(
      x, o2buf, selpos, unionm, out);
}